// Round 7
// baseline (31.418 us; speedup 1.0000x reference)
//
#include <hip/hip_runtime.h>

typedef float v2f __attribute__((ext_vector_type(2)));

constexpr float MARGIN = 0.3f;
constexpr float INV2PI = 0.15915494309189535f;

__device__ __forceinline__ v2f mk2(float x, float y) { v2f r; r.x = x; r.y = y; return r; }

__device__ __forceinline__ void sincos_hw(float rev, float& s, float& c) {
  s = __builtin_amdgcn_sinf(rev);   // input in revolutions
  c = __builtin_amdgcn_cosf(rev);
}

// SoA state: R[w] = (re_{2w}, re_{2w+1}), I[w] = (im_{2w}, im_{2w+1}), w=0..7.
// Amp bits (b3 b2 b1 b0): qubit q <-> bit (3-q); word w = i>>1 = (b3,b2,b1), half = b0.
//
// Simulates layer1 (product state, RZ as diag(1,e^{iz}), global phase dropped)
// + inter-layer CNOT ladder (folded as a compile-time permutation)
// + layer-2 RY. Final RZ layer is merged into the overlap (delta angles);
// final CNOT ladder cancels in the overlap.
//
// CNOT-ladder source map (derived by composing the three CNOTs):
//   state'[i3,i2,i1,i0] = state[i3, i2^i3, i1^i2, i0^i1]
// -> per dest word w=(i3,i2,i1): src t3-index k = (i3, i2^i3, i1^i2) = tab[w],
//    half-swap when i1=1 (odd w).
__device__ __forceinline__ void sim_core(const float ry[8], const float rz[8],
                                         v2f R[8], v2f I[8]) {
  // --- layer-1 per-qubit factors: u_q = (c0, p1r + i p1i) ---
  float c0[4], p1r[4], p1i[4];
#pragma unroll
  for (int q = 0; q < 4; ++q) {
    float sy, cy; sincos_hw(ry[q] * (0.5f * INV2PI), sy, cy);
    float sz, cz; sincos_hw(rz[q] * INV2PI, sz, cz);
    c0[q] = cy; p1r[q] = sy * cz; p1i[q] = sy * sz;
  }
  // scalar tree over qubits 0..2
  float t2r[4], t2i[4];
  t2r[0] = c0[0]*c0[1];                     t2i[0] = 0.0f;
  t2r[1] = c0[0]*p1r[1];                    t2i[1] = c0[0]*p1i[1];
  t2r[2] = p1r[0]*c0[1];                    t2i[2] = p1i[0]*c0[1];
  t2r[3] = p1r[0]*p1r[1] - p1i[0]*p1i[1];   t2i[3] = p1r[0]*p1i[1] + p1i[0]*p1r[1];
  float t3r[8], t3i[8];
#pragma unroll
  for (int k = 0; k < 4; ++k) {
    t3r[2*k]   = t2r[k]*c0[2];                  t3i[2*k]   = t2i[k]*c0[2];
    t3r[2*k+1] = t2r[k]*p1r[2] - t2i[k]*p1i[2]; t3i[2*k+1] = t2r[k]*p1i[2] + t2i[k]*p1r[2];
  }
  // emit qubit-3 factor with CNOT-ladder permutation folded in
  constexpr int tab[8] = {0, 1, 3, 2, 6, 7, 5, 4};
  const float c3 = c0[3], qr = p1r[3], qi = p1i[3];
#pragma unroll
  for (int w = 0; w < 8; ++w) {
    const int k = tab[w];
    const float e0r = t3r[k]*c3,             e0i = t3i[k]*c3;              // b0=0
    const float e1r = t3r[k]*qr - t3i[k]*qi, e1i = t3r[k]*qi + t3i[k]*qr;  // b0=1
    if (w & 1) { R[w] = mk2(e1r, e0r); I[w] = mk2(e1i, e0i); }   // half-swapped
    else       { R[w] = mk2(e0r, e1r); I[w] = mk2(e0i, e1i); }
  }

  // --- layer-2 RY (all elementwise with scalar splats; q=3 within-word) ---
  float sy[4], cy[4];
#pragma unroll
  for (int q = 0; q < 4; ++q) sincos_hw(ry[4+q] * (0.5f * INV2PI), sy[q], cy[q]);
  // q=0: amp bit3 = word bit2: pairs (w, w+4), w=0..3
#pragma unroll
  for (int w = 0; w < 4; ++w) {
    const v2f r0 = R[w], r1 = R[w+4], i0 = I[w], i1 = I[w+4];
    R[w]   = cy[0]*r0 - sy[0]*r1;  R[w+4] = sy[0]*r0 + cy[0]*r1;
    I[w]   = cy[0]*i0 - sy[0]*i1;  I[w+4] = sy[0]*i0 + cy[0]*i1;
  }
  // q=1: amp bit2 = word bit1: pairs (w, w+2), w in {0,1,4,5}
#pragma unroll
  for (int m = 0; m < 4; ++m) {
    const int w = (m & 1) | ((m & 2) << 1);   // 0,1,4,5
    const v2f r0 = R[w], r1 = R[w+2], i0 = I[w], i1 = I[w+2];
    R[w]   = cy[1]*r0 - sy[1]*r1;  R[w+2] = sy[1]*r0 + cy[1]*r1;
    I[w]   = cy[1]*i0 - sy[1]*i1;  I[w+2] = sy[1]*i0 + cy[1]*i1;
  }
  // q=2: amp bit1 = word bit0: pairs (w, w+1), w in {0,2,4,6}
#pragma unroll
  for (int m = 0; m < 4; ++m) {
    const int w = 2*m;
    const v2f r0 = R[w], r1 = R[w+1], i0 = I[w], i1 = I[w+1];
    R[w]   = cy[2]*r0 - sy[2]*r1;  R[w+1] = sy[2]*r0 + cy[2]*r1;
    I[w]   = cy[2]*i0 - sy[2]*i1;  I[w+1] = sy[2]*i0 + cy[2]*i1;
  }
  // q=3: amp bit0 = half: 2x2 rotation within each word
#pragma unroll
  for (int w = 0; w < 8; ++w) {
    const v2f r = R[w], i = I[w];
    R[w] = cy[3]*r + sy[3]*mk2(-r.y, r.x);
    I[w] = cy[3]*i + sy[3]*mk2(-i.y, i.x);
  }
}

// Apply merged final-RZ delta phases (dz[q] = z_x[q] - z_a[q]) to X, then |<A|X>|^2.
__device__ __forceinline__ float fid_soa(const v2f AR[8], const v2f AI[8],
                                         v2f XR[8], v2f XI[8], const float dz[4]) {
  float sz[4], cz[4];
#pragma unroll
  for (int q = 0; q < 4; ++q) sincos_hw(dz[q] * INV2PI, sz[q], cz[q]);
  // q=0: amp bit3 -> words 4..7 (full-word phase, elementwise)
#pragma unroll
  for (int w = 4; w < 8; ++w) {
    const v2f r = XR[w], i = XI[w];
    XR[w] = cz[0]*r - sz[0]*i;  XI[w] = sz[0]*r + cz[0]*i;
  }
  // q=1: amp bit2 -> words {2,3,6,7}
#pragma unroll
  for (int m = 0; m < 4; ++m) {
    const int w = (m & 1) | 2 | ((m & 2) << 1);   // 2,3,6,7
    const v2f r = XR[w], i = XI[w];
    XR[w] = cz[1]*r - sz[1]*i;  XI[w] = sz[1]*r + cz[1]*i;
  }
  // q=2: amp bit1 -> odd words
#pragma unroll
  for (int m = 0; m < 4; ++m) {
    const int w = 2*m + 1;
    const v2f r = XR[w], i = XI[w];
    XR[w] = cz[2]*r - sz[2]*i;  XI[w] = sz[2]*r + cz[2]*i;
  }
  // q=3: amp bit0 -> hi halves only: X' = X*{1,cz} -/+ ...
  const v2f Cv = mk2(1.0f, cz[3]), Sv = mk2(0.0f, sz[3]);
#pragma unroll
  for (int w = 0; w < 8; ++w) {
    const v2f r = XR[w], i = XI[w];
    XR[w] = r*Cv - i*Sv;  XI[w] = i*Cv + r*Sv;
  }
  // dot: conj(A).X
  v2f s1 = mk2(0.f, 0.f), s2 = mk2(0.f, 0.f);
#pragma unroll
  for (int w = 0; w < 8; ++w) {
    s1 += AR[w]*XR[w];  s1 += AI[w]*XI[w];
    s2 += AR[w]*XI[w];  s2 -= AI[w]*XR[w];
  }
  const float ovr = s1.x + s1.y;
  const float ovi = s2.x + s2.y;
  return ovr*ovr + ovi*ovi;
}

__device__ __forceinline__ void load8(const float* __restrict__ p, int b, float a[8]) {
  const float4* v = reinterpret_cast<const float4*>(p) + (size_t)b * 2;
  float4 x0 = v[0], x1 = v[1];
  a[0]=x0.x; a[1]=x0.y; a[2]=x0.z; a[3]=x0.w;
  a[4]=x1.x; a[5]=x1.y; a[6]=x1.z; a[7]=x1.w;
}

__global__ __launch_bounds__(256) void triplet_main(
    const float* __restrict__ a_ry, const float* __restrict__ a_rz,
    const float* __restrict__ p_ry, const float* __restrict__ p_rz,
    const float* __restrict__ n_ry, const float* __restrict__ n_rz,
    float* __restrict__ block_sums, int batch) {
  const int b = blockIdx.x * blockDim.x + threadIdx.x;

  float loss = 0.0f;
  if (b < batch) {
    float ry[8], rz[8], arz2[4];

    // anchor
    load8(a_ry, b, ry); load8(a_rz, b, rz);
#pragma unroll
    for (int q = 0; q < 4; ++q) arz2[q] = rz[4 + q];
    v2f AR[8], AI[8];
    sim_core(ry, rz, AR, AI);

    // positive
    load8(p_ry, b, ry); load8(p_rz, b, rz);
    v2f XR[8], XI[8];
    sim_core(ry, rz, XR, XI);
    float dz[4];
#pragma unroll
    for (int q = 0; q < 4; ++q) dz[q] = rz[4 + q] - arz2[q];
    const float fid_pos = fid_soa(AR, AI, XR, XI, dz);

    // negative (reuse XR/XI)
    load8(n_ry, b, ry); load8(n_rz, b, rz);
    sim_core(ry, rz, XR, XI);
#pragma unroll
    for (int q = 0; q < 4; ++q) dz[q] = rz[4 + q] - arz2[q];
    const float fid_neg = fid_soa(AR, AI, XR, XI, dz);

    loss = fmaxf(MARGIN - fid_pos + fid_neg, 0.0f);
  }

  // wave (64) reduce, then LDS across the 4 waves
#pragma unroll
  for (int off = 32; off >= 1; off >>= 1)
    loss += __shfl_down(loss, off, 64);

  __shared__ float wsum[4];
  const int lane = threadIdx.x & 63;
  const int wid  = threadIdx.x >> 6;
  if (lane == 0) wsum[wid] = loss;
  __syncthreads();
  if (threadIdx.x == 0) {
    block_sums[blockIdx.x] = wsum[0] + wsum[1] + wsum[2] + wsum[3];
  }
}

__global__ __launch_bounds__(256) void triplet_reduce(
    const float* __restrict__ block_sums, int nblocks, float* __restrict__ out, float inv_batch) {
  float s = 0.0f;
  for (int i = threadIdx.x; i < nblocks; i += 256) s += block_sums[i];
#pragma unroll
  for (int off = 32; off >= 1; off >>= 1)
    s += __shfl_down(s, off, 64);

  __shared__ float wsum[4];
  const int lane = threadIdx.x & 63;
  const int wid  = threadIdx.x >> 6;
  if (lane == 0) wsum[wid] = s;
  __syncthreads();
  if (threadIdx.x == 0) {
    out[0] = (wsum[0] + wsum[1] + wsum[2] + wsum[3]) * inv_batch;
  }
}

extern "C" void kernel_launch(void* const* d_in, const int* in_sizes, int n_in,
                              void* d_out, int out_size, void* d_ws, size_t ws_size,
                              hipStream_t stream) {
  const float* a_ry = (const float*)d_in[0];
  const float* a_rz = (const float*)d_in[1];
  const float* p_ry = (const float*)d_in[2];
  const float* p_rz = (const float*)d_in[3];
  const float* n_ry = (const float*)d_in[4];
  const float* n_rz = (const float*)d_in[5];
  float* out = (float*)d_out;

  const int batch = in_sizes[0] / 8;            // NL*NQ = 8 angles per element
  const int nblocks = (batch + 255) / 256;      // 2048
  float* block_sums = (float*)d_ws;

  triplet_main<<<nblocks, 256, 0, stream>>>(a_ry, a_rz, p_ry, p_rz, n_ry, n_rz,
                                            block_sums, batch);
  triplet_reduce<<<1, 256, 0, stream>>>(block_sums, nblocks, out, 1.0f / (float)batch);
}

// Round 8
// 28.609 us; speedup vs baseline: 1.0982x; 1.0982x over previous
//
#include <hip/hip_runtime.h>

typedef float v2f __attribute__((ext_vector_type(2)));

constexpr int NQ = 4;
constexpr int DIM = 16;          // 2^NQ
constexpr float MARGIN = 0.3f;
constexpr float INV2PI = 0.15915494309189535f;

__device__ __forceinline__ v2f mk2(float x, float y) { v2f r; r.x = x; r.y = y; return r; }

// complex multiply a*b where bs = {-b.y, b.x} is precomputed.
__device__ __forceinline__ v2f cmul_pre(v2f a, v2f b, v2f bs) {
  return a.xx * b + a.yy * bs;
}

__device__ __forceinline__ void sincos_hw(float rev, float& s, float& c) {
  s = __builtin_amdgcn_sinf(rev);   // input in revolutions
  c = __builtin_amdgcn_cosf(rev);
}

// CNOT ladder CNOT(q,q+1), q=0..2; qubit q == flat bit (3-q). Free permutation.
__device__ __forceinline__ void cnot_ladder(v2f s[DIM]) {
#pragma unroll
  for (int q = 0; q < NQ - 1; ++q) {
    const int pc = 1 << (NQ - 1 - q);
    const int pt = 1 << (NQ - 2 - q);
#pragma unroll
    for (int i = 0; i < DIM; ++i) {
      if ((i & pc) && !(i & pt)) {
        const int j = i | pt;
        v2f t = s[i]; s[i] = s[j]; s[j] = t;
      }
    }
  }
}

// Layer-1 product state (RZ as diag(1,e^{i z}), global phase dropped) + CNOT
// ladder + layer-2 RY butterflies. Final RZ layer is merged into the overlap
// (delta-angle phase tree); final CNOT ladder cancels in the overlap.
__device__ __forceinline__ void sim_core(const float ry[8], const float rz[8], v2f s[DIM]) {
  float c0[NQ]; v2f p1[NQ], p1s[NQ];
#pragma unroll
  for (int q = 0; q < NQ; ++q) {
    float sy, cy; sincos_hw(ry[q] * (0.5f * INV2PI), sy, cy);
    float sz, cz; sincos_hw(rz[q] * INV2PI, sz, cz);
    c0[q]  = cy;
    p1[q]  = mk2(sy * cz, sy * sz);
    p1s[q] = mk2(-p1[q].y, p1[q].x);
  }
  // tensor-product tree; qubit q is flat bit (3-q)
  v2f t2[4];
  t2[0] = mk2(c0[0] * c0[1], 0.0f);
  t2[1] = c0[0] * p1[1];
  t2[2] = c0[1] * p1[0];
  t2[3] = cmul_pre(p1[0], p1[1], p1s[1]);
  v2f t3[8];
#pragma unroll
  for (int k = 0; k < 4; ++k) {
    t3[2*k]   = t2[k] * c0[2];
    t3[2*k+1] = cmul_pre(t2[k], p1[2], p1s[2]);
  }
#pragma unroll
  for (int k = 0; k < 8; ++k) {
    s[2*k]   = t3[k] * c0[3];
    s[2*k+1] = cmul_pre(t3[k], p1[3], p1s[3]);
  }

  cnot_ladder(s);

  // layer-2 RY butterflies
#pragma unroll
  for (int q = 0; q < NQ; ++q) {
    const int bit = 1 << (NQ - 1 - q);
    float sy, cy; sincos_hw(ry[4 + q] * (0.5f * INV2PI), sy, cy);
#pragma unroll
    for (int i = 0; i < DIM; ++i) {
      if (i & bit) continue;
      const int j = i | bit;
      const v2f a0 = s[i], a1 = s[j];
      s[i] = cy * a0 - sy * a1;
      s[j] = sy * a0 + cy * a1;
    }
  }
}

// |<a| PΔ |x>|^2 with PΔ = ⊗_q diag(1, e^{i dz_q}) folded into the dot via a
// per-qubit contraction tree:  OV = Σ_i conj(a_i) x_i Π_q ph_q^{bit_q(i)}.
// Contract bit0 (qubit 3) first, then bit1, bit2, bit3.
__device__ __forceinline__ float fid_tree(const v2f a[DIM], const v2f x[DIM],
                                          const float dz[NQ]) {
  v2f ph[NQ], phs[NQ];
#pragma unroll
  for (int q = 0; q < NQ; ++q) {
    float s, c; sincos_hw(dz[q] * INV2PI, s, c);
    ph[q] = mk2(c, s); phs[q] = mk2(-s, c);
  }
  // d_i = conj(a_i) * x_i
  v2f d[DIM];
#pragma unroll
  for (int i = 0; i < DIM; ++i) {
    d[i] = mk2(a[i].x * x[i].x + a[i].y * x[i].y,
               a[i].x * x[i].y - a[i].y * x[i].x);
  }
  v2f e[8];
#pragma unroll
  for (int j = 0; j < 8; ++j) e[j] = d[2*j] + cmul_pre(d[2*j+1], ph[3], phs[3]);
  v2f f[4];
#pragma unroll
  for (int k = 0; k < 4; ++k) f[k] = e[2*k] + cmul_pre(e[2*k+1], ph[2], phs[2]);
  v2f g[2];
#pragma unroll
  for (int m = 0; m < 2; ++m) g[m] = f[2*m] + cmul_pre(f[2*m+1], ph[1], phs[1]);
  const v2f ov = g[0] + cmul_pre(g[1], ph[0], phs[0]);
  return ov.x * ov.x + ov.y * ov.y;
}

__device__ __forceinline__ void load8(const float* __restrict__ p, int b, float a[8]) {
  const float4* v = reinterpret_cast<const float4*>(p) + (size_t)b * 2;
  float4 x0 = v[0], x1 = v[1];
  a[0]=x0.x; a[1]=x0.y; a[2]=x0.z; a[3]=x0.w;
  a[4]=x1.x; a[5]=x1.y; a[6]=x1.z; a[7]=x1.w;
}

__global__ __launch_bounds__(256) void triplet_main(
    const float* __restrict__ a_ry, const float* __restrict__ a_rz,
    const float* __restrict__ p_ry, const float* __restrict__ p_rz,
    const float* __restrict__ n_ry, const float* __restrict__ n_rz,
    float* __restrict__ block_sums, int batch) {
  const int b = blockIdx.x * blockDim.x + threadIdx.x;

  float loss = 0.0f;
  if (b < batch) {
    float ry[8], rz[8], arz2[NQ];

    // anchor (final RZ merged into the dots, final CNOT ladder cancelled)
    load8(a_ry, b, ry); load8(a_rz, b, rz);
#pragma unroll
    for (int q = 0; q < NQ; ++q) arz2[q] = rz[4 + q];
    v2f as[DIM];
    sim_core(ry, rz, as);

    // positive
    load8(p_ry, b, ry); load8(p_rz, b, rz);
    v2f xs[DIM];
    sim_core(ry, rz, xs);
    float dz[NQ];
#pragma unroll
    for (int q = 0; q < NQ; ++q) dz[q] = rz[4 + q] - arz2[q];
    const float fid_pos = fid_tree(as, xs, dz);

    // negative (reuse xs)
    load8(n_ry, b, ry); load8(n_rz, b, rz);
    sim_core(ry, rz, xs);
#pragma unroll
    for (int q = 0; q < NQ; ++q) dz[q] = rz[4 + q] - arz2[q];
    const float fid_neg = fid_tree(as, xs, dz);

    loss = fmaxf(MARGIN - fid_pos + fid_neg, 0.0f);
  }

  // wave (64) reduce, then LDS across the 4 waves
#pragma unroll
  for (int off = 32; off >= 1; off >>= 1)
    loss += __shfl_down(loss, off, 64);

  __shared__ float wsum[4];
  const int lane = threadIdx.x & 63;
  const int wid  = threadIdx.x >> 6;
  if (lane == 0) wsum[wid] = loss;
  __syncthreads();
  if (threadIdx.x == 0) {
    block_sums[blockIdx.x] = wsum[0] + wsum[1] + wsum[2] + wsum[3];
  }
}

__global__ __launch_bounds__(256) void triplet_reduce(
    const float* __restrict__ block_sums, int nblocks, float* __restrict__ out, float inv_batch) {
  float s = 0.0f;
  for (int i = threadIdx.x; i < nblocks; i += 256) s += block_sums[i];
#pragma unroll
  for (int off = 32; off >= 1; off >>= 1)
    s += __shfl_down(s, off, 64);

  __shared__ float wsum[4];
  const int lane = threadIdx.x & 63;
  const int wid  = threadIdx.x >> 6;
  if (lane == 0) wsum[wid] = s;
  __syncthreads();
  if (threadIdx.x == 0) {
    out[0] = (wsum[0] + wsum[1] + wsum[2] + wsum[3]) * inv_batch;
  }
}

extern "C" void kernel_launch(void* const* d_in, const int* in_sizes, int n_in,
                              void* d_out, int out_size, void* d_ws, size_t ws_size,
                              hipStream_t stream) {
  const float* a_ry = (const float*)d_in[0];
  const float* a_rz = (const float*)d_in[1];
  const float* p_ry = (const float*)d_in[2];
  const float* p_rz = (const float*)d_in[3];
  const float* n_ry = (const float*)d_in[4];
  const float* n_rz = (const float*)d_in[5];
  float* out = (float*)d_out;

  const int batch = in_sizes[0] / 8;            // NL*NQ = 8 angles per element
  const int nblocks = (batch + 255) / 256;      // 2048
  float* block_sums = (float*)d_ws;

  triplet_main<<<nblocks, 256, 0, stream>>>(a_ry, a_rz, p_ry, p_rz, n_ry, n_rz,
                                            block_sums, batch);
  triplet_reduce<<<1, 256, 0, stream>>>(block_sums, nblocks, out, 1.0f / (float)batch);
}